// Round 3
// baseline (699.722 us; speedup 1.0000x reference)
//
#include <hip/hip_runtime.h>
#include <hip/hip_bf16.h>

// Problem constants (SpatialAttention): B=32, C=273, T=3000, O=270, D=2*32^2=2048
// Dtypes: inputs float32, OUTPUT float32 (reference dtypes; R1/R2 failures
// triangulate this — see journal).
#define NB 32
#define NC 273
#define NT 3000
#define NO 270
#define ND 2048

// Workspace layout:
//   emb   : NB*NC*ND bf16  = 35,782,656 bytes @ offset 0
//   scores: NB*NO*NC fp32  =  9,434,880 bytes @ offset 35,782,656 (softmaxed in place -> weights)
#define EMB_BYTES (35782656UL)

__device__ __forceinline__ float bf_lo(unsigned int u) { return __uint_as_float(u << 16); }
__device__ __forceinline__ float bf_hi(unsigned int u) { return __uint_as_float(u & 0xffff0000u); }
__device__ __forceinline__ unsigned short f2bf(float f) {
  __hip_bfloat16 h = __float2bfloat16(f);  // RTN-even
  unsigned short s;
  __builtin_memcpy(&s, &h, 2);
  return s;
}

// ---------------------------------------------------------------------------
// Kernel 1: Fourier embedding. One block per (b,c) channel; 256 thr x 8 elems.
// emb[bc][d] = d<1024 ? sin(2pi*(px*i+py*j)) : cos(...), i=(d&1023)>>5, j=d&31
// Writes bf16 (ws intermediate; error contribution ~1e-3, within threshold).
// ---------------------------------------------------------------------------
__global__ void emb_kernel(const float* __restrict__ layout,
                           __hip_bfloat16* __restrict__ emb) {
  const int bc = blockIdx.x;
  const float x = layout[2 * bc];
  const float y = layout[2 * bc + 1];
  const float inv = 1.0f / 1.2f;
  const float px = (x + 0.1f) * inv;
  const float py = (y + 0.1f) * inv;
  const float two_pi = 6.283185307179586f;

  const int d0 = threadIdx.x * 8;        // 8 contiguous elems per thread
  const bool is_sin = d0 < 1024;         // wave-uniform (threads 0..127 sin)
  const int dd0 = d0 & 1023;
  const int i = dd0 >> 5;
  const int j = dd0 & 31;                // multiple of 8, j+7 <= 31: i constant
  const float base = px * (float)i + py * (float)j;

  unsigned short h[8];
#pragma unroll
  for (int s = 0; s < 8; ++s) {
    const float ph = two_pi * (base + py * (float)s);
    const float v = is_sin ? sinf(ph) : cosf(ph);
    h[s] = f2bf(v);
  }
  uint4 u;
  u.x = (unsigned)h[0] | ((unsigned)h[1] << 16);
  u.y = (unsigned)h[2] | ((unsigned)h[3] << 16);
  u.z = (unsigned)h[4] | ((unsigned)h[5] << 16);
  u.w = (unsigned)h[6] | ((unsigned)h[7] << 16);
  *reinterpret_cast<uint4*>(emb + (size_t)bc * ND + d0) = u;
}

// ---------------------------------------------------------------------------
// Kernel 2: scores[b,o,c] = sum_d heads[o,d]*emb[b,c,d].  NT-GEMM, 64x64 tile,
// K-chunk 32. LDS stored transposed [k][row] (pad 68 -> 16B-aligned float4
// reads => ds_read_b128 in the inner loop).
// heads: float32.  emb: bf16 (ws).
// grid = (ceil(273/64)=5, ceil(270/64)=5, 32), block = 256
// ---------------------------------------------------------------------------
__global__ void scores_kernel(const float* __restrict__ heads,
                              const __hip_bfloat16* __restrict__ emb,
                              float* __restrict__ scores) {
  __shared__ float As[32][68];  // heads  [k][o-row]
  __shared__ float Bs[32][68];  // emb    [k][c-row]
  const int b = blockIdx.z;
  const int o0 = blockIdx.y * 64;
  const int c0 = blockIdx.x * 64;
  const int tid = threadIdx.x;
  const int tx = tid & 15, ty = tid >> 4;
  const int ldr = tid >> 2;        // 0..63 row
  const int ldk = (tid & 3) * 8;   // 0,8,16,24 k-offset (8 elems per thread)
  const __hip_bfloat16* embB = emb + (size_t)b * NC * ND;

  float acc[4][4] = {{0.f, 0.f, 0.f, 0.f}};

  for (int k0 = 0; k0 < ND; k0 += 32) {
    {
      const int o = o0 + ldr;
      float v[8];
      if (o < NO) {
        const float* p = heads + (size_t)o * ND + k0 + ldk;
        const float4 u0 = *reinterpret_cast<const float4*>(p);
        const float4 u1 = *reinterpret_cast<const float4*>(p + 4);
        v[0] = u0.x; v[1] = u0.y; v[2] = u0.z; v[3] = u0.w;
        v[4] = u1.x; v[5] = u1.y; v[6] = u1.z; v[7] = u1.w;
      } else {
#pragma unroll
        for (int s = 0; s < 8; ++s) v[s] = 0.f;
      }
#pragma unroll
      for (int s = 0; s < 8; ++s) As[ldk + s][ldr] = v[s];
    }
    {
      const int c = c0 + ldr;
      float v[8];
      if (c < NC) {
        const uint4 u = *reinterpret_cast<const uint4*>(embB + (size_t)c * ND + k0 + ldk);
        v[0] = bf_lo(u.x); v[1] = bf_hi(u.x); v[2] = bf_lo(u.y); v[3] = bf_hi(u.y);
        v[4] = bf_lo(u.z); v[5] = bf_hi(u.z); v[6] = bf_lo(u.w); v[7] = bf_hi(u.w);
      } else {
#pragma unroll
        for (int s = 0; s < 8; ++s) v[s] = 0.f;
      }
#pragma unroll
      for (int s = 0; s < 8; ++s) Bs[ldk + s][ldr] = v[s];
    }
    __syncthreads();
#pragma unroll
    for (int kk = 0; kk < 32; ++kk) {
      const float4 a4 = *reinterpret_cast<const float4*>(&As[kk][ty * 4]);
      const float4 b4 = *reinterpret_cast<const float4*>(&Bs[kk][tx * 4]);
      const float a[4] = {a4.x, a4.y, a4.z, a4.w};
      const float bb[4] = {b4.x, b4.y, b4.z, b4.w};
#pragma unroll
      for (int i2 = 0; i2 < 4; ++i2)
#pragma unroll
        for (int j2 = 0; j2 < 4; ++j2)
          acc[i2][j2] = fmaf(a[i2], bb[j2], acc[i2][j2]);
    }
    __syncthreads();
  }

#pragma unroll
  for (int i2 = 0; i2 < 4; ++i2) {
    const int o = o0 + ty * 4 + i2;
    if (o >= NO) continue;
#pragma unroll
    for (int j2 = 0; j2 < 4; ++j2) {
      const int c = c0 + tx * 4 + j2;
      if (c < NC) scores[((size_t)b * NO + o) * NC + c] = acc[i2][j2];
    }
  }
}

// ---------------------------------------------------------------------------
// Kernel 3: row softmax over C=273. One wave per (b,o) row; in place.
// grid = 8640/4 = 2160, block = 256 (4 waves)
// ---------------------------------------------------------------------------
__global__ void softmax_kernel(float* __restrict__ sw) {
  const int row = blockIdx.x * 4 + (threadIdx.x >> 6);
  const int lane = threadIdx.x & 63;
  float* p = sw + (size_t)row * NC;
  float v[5];
  float m = -3.0e38f;
#pragma unroll
  for (int k = 0; k < 5; ++k) {
    const int c = lane + k * 64;
    v[k] = (c < NC) ? p[c] : -3.0e38f;
    m = fmaxf(m, v[k]);
  }
#pragma unroll
  for (int off = 32; off > 0; off >>= 1) m = fmaxf(m, __shfl_xor(m, off));
  float s = 0.f;
#pragma unroll
  for (int k = 0; k < 5; ++k) {
    v[k] = expf(v[k] - m);  // OOB lanes: exp(-huge)=0
    s += v[k];
  }
#pragma unroll
  for (int off = 32; off > 0; off >>= 1) s += __shfl_xor(s, off);
  const float r = 1.0f / s;
#pragma unroll
  for (int k = 0; k < 5; ++k) {
    const int c = lane + k * 64;
    if (c < NC) p[c] = v[k] * r;
  }
}

// ---------------------------------------------------------------------------
// Kernel 4: out[b,o,t] = sum_c weights[b,o,c]*brain[b,c,t].  NN-GEMM,
// 64x64 tile, K-chunk 32, same LDS scheme ([k][row], pad 68).
// brain: float32.  out: float32 (float4 stores).
// grid = (ceil(3000/64)=47, 5, 32), block = 256
// ---------------------------------------------------------------------------
__global__ void out_kernel(const float* __restrict__ weights,
                           const float* __restrict__ brain,
                           float* __restrict__ out) {
  __shared__ float As[32][68];  // weights [k][o-row]
  __shared__ float Bs[32][68];  // brain   [k][t-col]
  const int b = blockIdx.z;
  const int o0 = blockIdx.y * 64;
  const int t0 = blockIdx.x * 64;
  const int tid = threadIdx.x;
  const int tx = tid & 15, ty = tid >> 4;
  const float* Wb = weights + (size_t)b * NO * NC;
  const float* Xb = brain + (size_t)b * NC * NT;

  const int ar = tid >> 2;          // 0..63  (o row)
  const int ac = (tid & 3) * 8;     // k-offset
  const int bk = tid >> 3;          // 0..31  (k row)
  const int btoff = (tid & 7) * 8;  // t-offset (8 floats = 2x16B)

  float acc[4][4] = {{0.f, 0.f, 0.f, 0.f}};

  for (int k0 = 0; k0 < NC; k0 += 32) {
    {
      const int o = o0 + ar;
#pragma unroll
      for (int s = 0; s < 8; ++s) {
        const int c = k0 + ac + s;
        As[ac + s][ar] = (o < NO && c < NC) ? Wb[(size_t)o * NC + c] : 0.f;
      }
    }
    {
      const int c = k0 + bk;
      const int t = t0 + btoff;
      float v[8];
      if (c < NC && t + 7 < NT) {
        const float* p = Xb + (size_t)c * NT + t;
        const float4 u0 = *reinterpret_cast<const float4*>(p);
        const float4 u1 = *reinterpret_cast<const float4*>(p + 4);
        v[0] = u0.x; v[1] = u0.y; v[2] = u0.z; v[3] = u0.w;
        v[4] = u1.x; v[5] = u1.y; v[6] = u1.z; v[7] = u1.w;
      } else {
#pragma unroll
        for (int s = 0; s < 8; ++s)
          v[s] = (c < NC && t + s < NT) ? Xb[(size_t)c * NT + t + s] : 0.f;
      }
#pragma unroll
      for (int s = 0; s < 8; ++s) Bs[bk][btoff + s] = v[s];
    }
    __syncthreads();
#pragma unroll
    for (int kk = 0; kk < 32; ++kk) {
      const float4 a4 = *reinterpret_cast<const float4*>(&As[kk][ty * 4]);
      const float4 b4 = *reinterpret_cast<const float4*>(&Bs[kk][tx * 4]);
      const float a[4] = {a4.x, a4.y, a4.z, a4.w};
      const float bb[4] = {b4.x, b4.y, b4.z, b4.w};
#pragma unroll
      for (int i2 = 0; i2 < 4; ++i2)
#pragma unroll
        for (int j2 = 0; j2 < 4; ++j2)
          acc[i2][j2] = fmaf(a[i2], bb[j2], acc[i2][j2]);
    }
    __syncthreads();
  }

#pragma unroll
  for (int i2 = 0; i2 < 4; ++i2) {
    const int o = o0 + ty * 4 + i2;
    if (o >= NO) continue;
    const int t = t0 + tx * 4;
    if (t >= NT) continue;  // 3000 % 4 == 0: either all 4 valid or none
    float4 st;
    st.x = acc[i2][0];
    st.y = acc[i2][1];
    st.z = acc[i2][2];
    st.w = acc[i2][3];
    *reinterpret_cast<float4*>(out + ((size_t)b * NO + o) * NT + t) = st;
  }
}

extern "C" void kernel_launch(void* const* d_in, const int* in_sizes, int n_in,
                              void* d_out, int out_size, void* d_ws, size_t ws_size,
                              hipStream_t stream) {
  // Identify inputs by element count (defensive; documented order is
  // brain_data, channel_layout, heads).
  const float* brain = (const float*)d_in[0];   // [32,273,3000] = 26,208,000
  const float* layout = (const float*)d_in[1];  // [32,273,2]    =     17,472
  const float* heads = (const float*)d_in[2];   // [270,2048]    =    552,960
  for (int i = 0; i < n_in; ++i) {
    if (in_sizes[i] == NB * NC * NT) brain = (const float*)d_in[i];
    else if (in_sizes[i] == NB * NC * 2) layout = (const float*)d_in[i];
    else if (in_sizes[i] == NO * ND) heads = (const float*)d_in[i];
  }
  float* out = (float*)d_out;  // [32,270,3000] fp32

  __hip_bfloat16* emb = (__hip_bfloat16*)d_ws;                   // 35.8 MB
  float* scores = (float*)((char*)d_ws + EMB_BYTES);             // 9.4 MB (-> weights)

  emb_kernel<<<NB * NC, 256, 0, stream>>>(layout, emb);
  scores_kernel<<<dim3(5, 5, NB), 256, 0, stream>>>(heads, emb, scores);
  softmax_kernel<<<(NB * NO) / 4, 256, 0, stream>>>(scores);
  out_kernel<<<dim3(47, 5, NB), 256, 0, stream>>>(scores, brain, out);
}

// Round 4
// 307.347 us; speedup vs baseline: 2.2767x; 2.2767x over previous
//
#include <hip/hip_runtime.h>
#include <hip/hip_bf16.h>
#include <hip/hip_fp16.h>

// SpatialAttention: B=32, C=273, T=3000, O=270, D=2048. fp32 in, fp32 out.
#define NB 32
#define NC 273
#define NT 3000
#define NO 270
#define ND 2048
#define CP 288  // C padded to 9*32 for out-GEMM K dimension

typedef _Float16 f16x8 __attribute__((ext_vector_type(8)));
typedef float f32x4 __attribute__((ext_vector_type(4)));

// Workspace layout (bytes). X^T overlaps emb (emb dead after scores_kernel):
//   [0,        35,782,656)  emb   _Float16 [NB][NC][ND]   (phase 1)
//   [0,        55,296,000)  X^T   _Float16 [NB][NT][CP]   (phase 2, clobbers emb)
//   [55296000, 64,730,880)  scores float   [NB][NO][NC]
//   [64730880, 69,707,520)  W     _Float16 [NB][NO][CP]   (softmaxed weights, zero-padded)
//   [69707520, 70,813,440)  headsh _Float16 [NO][ND]
// Peak ws = 70,813,440 B.
#define S_OFF 55296000UL
#define W_OFF 64730880UL
#define H_OFF 69707520UL

__device__ __forceinline__ unsigned short f2h_bits(float f) {
  _Float16 h = (_Float16)f;
  unsigned short u;
  __builtin_memcpy(&u, &h, 2);
  return u;
}

// ---------------------------------------------------------------------------
// heads fp32 -> fp16. 270 blocks x 256 thr x 8 elems (exact).
// ---------------------------------------------------------------------------
__global__ void heads_cvt_kernel(const float* __restrict__ heads,
                                 _Float16* __restrict__ hh) {
  const size_t idx = ((size_t)blockIdx.x * 256 + threadIdx.x) * 8;
  const float4 a = *reinterpret_cast<const float4*>(heads + idx);
  const float4 c = *reinterpret_cast<const float4*>(heads + idx + 4);
  f16x8 v;
  v[0] = (_Float16)a.x; v[1] = (_Float16)a.y; v[2] = (_Float16)a.z; v[3] = (_Float16)a.w;
  v[4] = (_Float16)c.x; v[5] = (_Float16)c.y; v[6] = (_Float16)c.z; v[7] = (_Float16)c.w;
  *reinterpret_cast<f16x8*>(hh + idx) = v;
}

// ---------------------------------------------------------------------------
// Fourier embedding -> fp16. One block per (b,c); 256 thr x 8 elems.
// ---------------------------------------------------------------------------
__global__ void emb_kernel(const float* __restrict__ layout,
                           _Float16* __restrict__ emb) {
  const int bc = blockIdx.x;
  const float x = layout[2 * bc];
  const float y = layout[2 * bc + 1];
  const float inv = 1.0f / 1.2f;
  const float px = (x + 0.1f) * inv;
  const float py = (y + 0.1f) * inv;
  const float two_pi = 6.283185307179586f;

  const int d0 = threadIdx.x * 8;
  const bool is_sin = d0 < 1024;
  const int dd0 = d0 & 1023;
  const int i = dd0 >> 5;
  const int j = dd0 & 31;
  const float base = px * (float)i + py * (float)j;

  unsigned short h[8];
#pragma unroll
  for (int s = 0; s < 8; ++s) {
    const float ph = two_pi * (base + py * (float)s);
    const float v = is_sin ? sinf(ph) : cosf(ph);
    h[s] = f2h_bits(v);
  }
  uint4 u;
  u.x = (unsigned)h[0] | ((unsigned)h[1] << 16);
  u.y = (unsigned)h[2] | ((unsigned)h[3] << 16);
  u.z = (unsigned)h[4] | ((unsigned)h[5] << 16);
  u.w = (unsigned)h[6] | ((unsigned)h[7] << 16);
  *reinterpret_cast<uint4*>(emb + (size_t)bc * ND + d0) = u;
}

// ---------------------------------------------------------------------------
// scores[b,o,c] = sum_d heads[o,d]*emb[b,c,d]. MFMA NT-GEMM.
// Tile M=64(o) x N=64(c), K-step 64 (32 iters). 4 waves in 2x2 grid, each
// wave 32x32 via 2x2 mfma_f32_16x16x32_f16. LDS pitch 72 halves (16B-aligned
// rows, 2-way max bank aliasing = free).
// grid = (5 c-tiles, 5 o-tiles, 32 b)
// ---------------------------------------------------------------------------
__global__ void scores_kernel(const _Float16* __restrict__ hh,
                              const _Float16* __restrict__ emb,
                              float* __restrict__ scores) {
  __shared__ _Float16 As[64][72];
  __shared__ _Float16 Bs[64][72];
  const int b = blockIdx.z, o0 = blockIdx.y * 64, c0 = blockIdx.x * 64;
  const int tid = threadIdx.x;
  const int lane = tid & 63, w = tid >> 6;
  const int wm = (w >> 1) * 32, wn = (w & 1) * 32;
  const int ln = lane & 15, quad = lane >> 4;
  const int sr = tid >> 2;        // staging row 0..63
  const int sk = (tid & 3) * 16;  // staging col offset (halves)
  const _Float16* embB = emb + (size_t)b * NC * ND;

  f32x4 acc[2][2] = {};

  for (int k0 = 0; k0 < ND; k0 += 64) {
    {
      const int o = o0 + sr;
      uint4 u0 = {0, 0, 0, 0}, u1 = {0, 0, 0, 0};
      if (o < NO) {
        const uint4* p = reinterpret_cast<const uint4*>(hh + (size_t)o * ND + k0 + sk);
        u0 = p[0]; u1 = p[1];
      }
      *reinterpret_cast<uint4*>(&As[sr][sk]) = u0;
      *reinterpret_cast<uint4*>(&As[sr][sk + 8]) = u1;
    }
    {
      const int c = c0 + sr;
      uint4 u0 = {0, 0, 0, 0}, u1 = {0, 0, 0, 0};
      if (c < NC) {
        const uint4* p = reinterpret_cast<const uint4*>(embB + (size_t)c * ND + k0 + sk);
        u0 = p[0]; u1 = p[1];
      }
      *reinterpret_cast<uint4*>(&Bs[sr][sk]) = u0;
      *reinterpret_cast<uint4*>(&Bs[sr][sk + 8]) = u1;
    }
    __syncthreads();
#pragma unroll
    for (int ks = 0; ks < 64; ks += 32) {
      const int kf = ks + quad * 8;
      const f16x8 a0 = *reinterpret_cast<const f16x8*>(&As[wm + ln][kf]);
      const f16x8 a1 = *reinterpret_cast<const f16x8*>(&As[wm + 16 + ln][kf]);
      const f16x8 b0 = *reinterpret_cast<const f16x8*>(&Bs[wn + ln][kf]);
      const f16x8 b1 = *reinterpret_cast<const f16x8*>(&Bs[wn + 16 + ln][kf]);
      acc[0][0] = __builtin_amdgcn_mfma_f32_16x16x32_f16(a0, b0, acc[0][0], 0, 0, 0);
      acc[0][1] = __builtin_amdgcn_mfma_f32_16x16x32_f16(a0, b1, acc[0][1], 0, 0, 0);
      acc[1][0] = __builtin_amdgcn_mfma_f32_16x16x32_f16(a1, b0, acc[1][0], 0, 0, 0);
      acc[1][1] = __builtin_amdgcn_mfma_f32_16x16x32_f16(a1, b1, acc[1][1], 0, 0, 0);
    }
    __syncthreads();
  }

  float* sB = scores + (size_t)b * NO * NC;
#pragma unroll
  for (int i = 0; i < 2; ++i) {
    const int ob = o0 + wm + 16 * i + quad * 4;
#pragma unroll
    for (int j = 0; j < 2; ++j) {
      const int c = c0 + wn + 16 * j + ln;
      if (c >= NC) continue;
#pragma unroll
      for (int r = 0; r < 4; ++r) {
        const int o = ob + r;
        if (o < NO) sB[(size_t)o * NC + c] = acc[i][j][r];
      }
    }
  }
}

// ---------------------------------------------------------------------------
// Row softmax over C=273, fp32 in -> fp16 weights out, zero-padded to CP=288.
// One wave per (b,o) row. grid = 8640/4, block 256.
// ---------------------------------------------------------------------------
__global__ void softmax_kernel(const float* __restrict__ sc,
                               _Float16* __restrict__ wq) {
  const int row = blockIdx.x * 4 + (threadIdx.x >> 6);
  const int lane = threadIdx.x & 63;
  const float* p = sc + (size_t)row * NC;
  _Float16* q = wq + (size_t)row * CP;
  float v[5];
  float m = -3.0e38f;
#pragma unroll
  for (int k = 0; k < 5; ++k) {
    const int c = lane + k * 64;
    v[k] = (c < NC) ? p[c] : -3.0e38f;
    m = fmaxf(m, v[k]);
  }
#pragma unroll
  for (int off = 32; off > 0; off >>= 1) m = fmaxf(m, __shfl_xor(m, off));
  float s = 0.f;
#pragma unroll
  for (int k = 0; k < 5; ++k) {
    v[k] = expf(v[k] - m);
    s += v[k];
  }
#pragma unroll
  for (int off = 32; off > 0; off >>= 1) s += __shfl_xor(s, off);
  const float r = 1.0f / s;
#pragma unroll
  for (int k = 0; k < 5; ++k) {
    const int c = lane + k * 64;
    if (c < NC) q[c] = (_Float16)(v[k] * r);
    else if (c < CP) q[c] = (_Float16)0.f;
  }
}

// ---------------------------------------------------------------------------
// brain fp32 [b][c][t] -> X^T fp16 [b][t][CP], zero-padded c>=273.
// 32x32 LDS tile (pad 33). grid = (94 t-tiles, 9 c-tiles, 32 b).
// ---------------------------------------------------------------------------
__global__ void transpose_kernel(const float* __restrict__ brain,
                                 _Float16* __restrict__ xh) {
  __shared__ float tile[32][33];
  const int b = blockIdx.z;
  const int c0 = blockIdx.y * 32;
  const int t0 = blockIdx.x * 32;
  const int tid = threadIdx.x;
  {
    const int cl = tid >> 3, tl = (tid & 7) * 4;
    const int c = c0 + cl;
    float4 v = {0.f, 0.f, 0.f, 0.f};
    if (c < NC) {
      const int t = t0 + tl;
      const float* p = brain + ((size_t)b * NC + c) * NT + t;
      if (t + 3 < NT) {
        v = *reinterpret_cast<const float4*>(p);
      } else {
        if (t + 0 < NT) v.x = p[0];
        if (t + 1 < NT) v.y = p[1];
        if (t + 2 < NT) v.z = p[2];
        if (t + 3 < NT) v.w = p[3];
      }
    }
    tile[cl][tl + 0] = v.x;
    tile[cl][tl + 1] = v.y;
    tile[cl][tl + 2] = v.z;
    tile[cl][tl + 3] = v.w;
  }
  __syncthreads();
  {
    const int tl = tid >> 3, cl = (tid & 7) * 4;
    const int t = t0 + tl;
    if (t < NT) {
      const unsigned short h0 = f2h_bits(tile[cl + 0][tl]);
      const unsigned short h1 = f2h_bits(tile[cl + 1][tl]);
      const unsigned short h2 = f2h_bits(tile[cl + 2][tl]);
      const unsigned short h3 = f2h_bits(tile[cl + 3][tl]);
      uint2 u;
      u.x = (unsigned)h0 | ((unsigned)h1 << 16);
      u.y = (unsigned)h2 | ((unsigned)h3 << 16);
      *reinterpret_cast<uint2*>(xh + ((size_t)b * NT + t) * CP + c0 + cl) = u;
    }
  }
}

// ---------------------------------------------------------------------------
// out[b,o,t] = sum_c W[b,o,c]*X^T[b,t,c]. MFMA NT-GEMM.
// Tile M=64(o) x N=128(t), K=CP=288, K-step 32 (9 iters). 4 waves 2x2; each
// wave 32x64 via 2x4 mfma tiles. LDS pitch 40 halves.
// grid = (24 t-tiles, 5 o-tiles, 32 b)
// ---------------------------------------------------------------------------
__global__ void out_kernel(const _Float16* __restrict__ wq,
                           const _Float16* __restrict__ xh,
                           float* __restrict__ out) {
  __shared__ _Float16 As[64][40];
  __shared__ _Float16 Bs[128][40];
  const int b = blockIdx.z, o0 = blockIdx.y * 64, t0 = blockIdx.x * 128;
  const int tid = threadIdx.x;
  const int lane = tid & 63, w = tid >> 6;
  const int wm = (w >> 1) * 32, wn = (w & 1) * 64;
  const int ln = lane & 15, quad = lane >> 4;
  const _Float16* Wb = wq + (size_t)b * NO * CP;
  const _Float16* Xb = xh + (size_t)b * NT * CP;

  const int ar = tid >> 2, ak = (tid & 3) * 8;   // A staging: 64 rows x 8 halves
  const int br = tid >> 1, bk = (tid & 1) * 16;  // B staging: 128 rows x 16 halves

  f32x4 acc[2][4] = {};

  for (int k0 = 0; k0 < CP; k0 += 32) {
    {
      const int o = o0 + ar;
      uint4 u = {0, 0, 0, 0};
      if (o < NO) u = *reinterpret_cast<const uint4*>(Wb + (size_t)o * CP + k0 + ak);
      *reinterpret_cast<uint4*>(&As[ar][ak]) = u;
    }
    {
      const int t = t0 + br;
      uint4 u0 = {0, 0, 0, 0}, u1 = {0, 0, 0, 0};
      if (t < NT) {
        const uint4* p = reinterpret_cast<const uint4*>(Xb + (size_t)t * CP + k0 + bk);
        u0 = p[0]; u1 = p[1];
      }
      *reinterpret_cast<uint4*>(&Bs[br][bk]) = u0;
      *reinterpret_cast<uint4*>(&Bs[br][bk + 8]) = u1;
    }
    __syncthreads();
    {
      const int kf = quad * 8;
      const f16x8 a0 = *reinterpret_cast<const f16x8*>(&As[wm + ln][kf]);
      const f16x8 a1 = *reinterpret_cast<const f16x8*>(&As[wm + 16 + ln][kf]);
#pragma unroll
      for (int j = 0; j < 4; ++j) {
        const f16x8 bj = *reinterpret_cast<const f16x8*>(&Bs[wn + 16 * j + ln][kf]);
        acc[0][j] = __builtin_amdgcn_mfma_f32_16x16x32_f16(a0, bj, acc[0][j], 0, 0, 0);
        acc[1][j] = __builtin_amdgcn_mfma_f32_16x16x32_f16(a1, bj, acc[1][j], 0, 0, 0);
      }
    }
    __syncthreads();
  }

  float* oB = out + (size_t)b * NO * NT;
#pragma unroll
  for (int i = 0; i < 2; ++i) {
    const int ob = o0 + wm + 16 * i + quad * 4;
#pragma unroll
    for (int j = 0; j < 4; ++j) {
      const int t = t0 + wn + 16 * j + ln;
      if (t >= NT) continue;
#pragma unroll
      for (int r = 0; r < 4; ++r) {
        const int o = ob + r;
        if (o < NO) oB[(size_t)o * NT + t] = acc[i][j][r];
      }
    }
  }
}

extern "C" void kernel_launch(void* const* d_in, const int* in_sizes, int n_in,
                              void* d_out, int out_size, void* d_ws, size_t ws_size,
                              hipStream_t stream) {
  const float* brain = (const float*)d_in[0];   // [32,273,3000]
  const float* layout = (const float*)d_in[1];  // [32,273,2]
  const float* heads = (const float*)d_in[2];   // [270,2048]
  for (int i = 0; i < n_in; ++i) {
    if (in_sizes[i] == NB * NC * NT) brain = (const float*)d_in[i];
    else if (in_sizes[i] == NB * NC * 2) layout = (const float*)d_in[i];
    else if (in_sizes[i] == NO * ND) heads = (const float*)d_in[i];
  }
  float* out = (float*)d_out;  // [32,270,3000]

  _Float16* emb = (_Float16*)d_ws;                       // [NB][NC][ND], phase 1
  _Float16* xh = (_Float16*)d_ws;                        // [NB][NT][CP], phase 2 (overlaps emb)
  float* scores = (float*)((char*)d_ws + S_OFF);         // [NB][NO][NC]
  _Float16* wq = (_Float16*)((char*)d_ws + W_OFF);       // [NB][NO][CP]
  _Float16* hh = (_Float16*)((char*)d_ws + H_OFF);       // [NO][ND]

  heads_cvt_kernel<<<NO, 256, 0, stream>>>(heads, hh);
  emb_kernel<<<NB * NC, 256, 0, stream>>>(layout, emb);
  scores_kernel<<<dim3(5, 5, NB), 256, 0, stream>>>(hh, emb, scores);
  softmax_kernel<<<(NB * NO) / 4, 256, 0, stream>>>(scores, wq);
  transpose_kernel<<<dim3((NT + 31) / 32, CP / 32, NB), 256, 0, stream>>>(brain, xh);
  out_kernel<<<dim3((NT + 127) / 128, 5, NB), 256, 0, stream>>>(wq, xh, out);
}